// Round 1
// baseline (417.766 us; speedup 1.0000x reference)
//
#include <hip/hip_runtime.h>
#include <hip/hip_bf16.h>

#define BN    32768   // B*N
#define KNB   12
#define DIM   128

typedef __attribute__((ext_vector_type(8))) short bf16x8;
typedef __attribute__((ext_vector_type(4))) float f32x4;

__device__ inline unsigned short f2b(float x) {
    union { float f; unsigned u; } v; v.f = x;
    unsigned r = v.u + 0x7fffu + ((v.u >> 16) & 1u);   // RNE
    return (unsigned short)(r >> 16);
}
__device__ inline unsigned pack2(float a, float b) {   // v_cvt_pk_bf16_f32 on gfx950
    __hip_bfloat162 h = __float22bfloat162_rn(make_float2(a, b));
    unsigned u; __builtin_memcpy(&u, &h, 4); return u;
}
__device__ inline float2 unpack2(unsigned u) {
    __hip_bfloat162 h; __builtin_memcpy(&h, &u, 4);
    return __bfloat1622float2(h);
}

// Raw barrier: publish LDS (lgkmcnt) but do NOT drain vmcnt — keeps the
// cross-group global-load prefetch in flight across phase boundaries.
// (__syncthreads would emit s_waitcnt vmcnt(0) and kill the pipeline.)
__device__ inline void bar_lds() {
    asm volatile("s_waitcnt lgkmcnt(0)" ::: "memory");
    __builtin_amdgcn_s_barrier();
    asm volatile("" ::: "memory");
}

// ---------------------------------------------------------------------------
// Prep: w1 (128x128 part) and w3 (256x128) -> bf16 MFMA B-fragment order.
// frag fi, lane, j -> B[k = ks*32 + (lane>>4)*8 + j][n = nt*16 + (lane&15)]
// w1f: fi = nt*4 + ks;  w3f: fi = nt*8 + ks
// ---------------------------------------------------------------------------
__global__ void prep_kernel(const float* __restrict__ w1, const float* __restrict__ w3,
                            unsigned short* __restrict__ w1f, unsigned short* __restrict__ w3f) {
    int idx = blockIdx.x * 256 + threadIdx.x;
    if (idx < 16384) {
        int j = idx & 7, lane = (idx >> 3) & 63, fi = idx >> 9;
        int nt = fi >> 2, ks = fi & 3;
        int k = ks * 32 + (lane >> 4) * 8 + j;
        int n = nt * 16 + (lane & 15);
        w1f[idx] = f2b(w1[k * DIM + n]);
    }
    if (idx < 32768) {
        int j = idx & 7, lane = (idx >> 3) & 63, fi = idx >> 9;
        int nt = fi >> 3, ks = fi & 7;
        int k = ks * 32 + (lane >> 4) * 8 + j;
        int n = nt * 16 + (lane & 15);
        w3f[idx] = f2b(w3[k * DIM + n]);
    }
}

// ---------------------------------------------------------------------------
// Fused kernel, block = 8 nodes/group (M1 = 96 (node,k) rows), NG=4 groups
// per block with a cross-group prefetch pipeline:
//   phase 0: GEMM1(g)   [issue nbr k=0..5, ext, nw, (self) loads for g+1]
//   phase 1: softmax(g) || A2 self-stage(g) [reload self for g+1]
//   phase 2: agg(g)     [issue nbr k=6..11 loads for g+1]
//   phase 3: write featb(g+1) halves around GEMM2(g)
// Grid = BN/(T1*NG) = 1024 = 256 CU x 4 resident blocks (LDS 36 KB/block).
// ---------------------------------------------------------------------------
#define T1   8
#define NG   4
#define M1   96
#define LDA1 136    // shorts; 16B-multiple (b128-aligned), +8 pad
#define LDA2 264    // shorts; 16B-multiple, +8 pad

__global__ __launch_bounds__(256, 4) void fused_kernel(
    const float* __restrict__ nbr_g,   // [BN,12,128]
    const float* __restrict__ nw_g,    // [BN,12]
    const float* __restrict__ ext_g,   // [BN,128]
    const float* __restrict__ selfv,   // [BN,128]
    const float* __restrict__ w1,      // [129,128] (row 128 used in epilogue)
    const float* __restrict__ w2,      // [128]
    const unsigned short* __restrict__ w1f,
    const unsigned short* __restrict__ w3f,
    float* __restrict__ out)           // [BN,128]
{
    __shared__ unsigned short featb[M1 * LDA1];          // 26112 B
    __shared__ unsigned short A2[16 * LDA2];             // 8448 B
    __shared__ float logits_p[4][M1];                    // 1536 B
    __shared__ float wts[M1];                            // 384 B
    __shared__ float nwv[M1];                            // 384 B

    const int tid  = threadIdx.x;
    const int lane = tid & 63;
    const int wv   = tid >> 6;

    const int node = tid >> 5;          // 0..7
    const int c4   = tid & 31;          // float4 column

    const int m    = lane & 15;
    const int quad = lane >> 4;
    const int nt0  = wv * 2;
    const int nt1  = wv * 2 + 1;

    // group-invariant weight scalars (per-lane)
    const float w2v0 = w2[nt0 * 16 + m], w2v1 = w2[nt1 * 16 + m];
    const float w1l0 = w1[DIM * DIM + nt0 * 16 + m];
    const float w1l1 = w1[DIM * DIM + nt1 * 16 + m];
    const bf16x8* w1fv = (const bf16x8*)w1f;
    const bf16x8* w3fv = (const bf16x8*)w3f;

    const size_t base = (size_t)blockIdx.x * (NG * T1);   // first node row

    // pipeline registers
    float4 nA[6], nB[6];
    float4 evC, evN, selfC;

    // ---- prologue: stage group 0 fully ----
    {
        const float4* nsrc = (const float4*)(nbr_g + base * (KNB * DIM));
        evC   = *(const float4*)(ext_g + (base + node) * DIM + c4 * 4);
        selfC = *(const float4*)(selfv + (base + node) * DIM + c4 * 4);
        float nw0 = 0.f;
        if (tid < M1) nw0 = nw_g[base * KNB + tid];
        float4 nv[KNB];
        #pragma unroll
        for (int k = 0; k < KNB; ++k) nv[k] = nsrc[node * (KNB * 32) + k * 32 + c4];
        #pragma unroll
        for (int k = 0; k < KNB; ++k) {
            uint2 pf;
            pf.x = pack2(nv[k].x * evC.x, nv[k].y * evC.y);
            pf.y = pack2(nv[k].z * evC.z, nv[k].w * evC.w);
            *(uint2*)&featb[(node * KNB + k) * LDA1 + c4 * 4] = pf;
        }
        if (tid < M1) nwv[tid] = nw0;
    }
    bar_lds();

    #pragma unroll 1
    for (int g = 0; g < NG; ++g) {
        const size_t bn0 = base + (size_t)g * T1;
        const size_t bn1 = bn0 + T1;
        const bool hasNext = (g + 1 < NG);
        float nwN = 0.f;

        // ---- phase 0: issue first-half prefetch for g+1, then GEMM1(g) ----
        if (hasNext) {
            const float4* nsrc = (const float4*)(nbr_g + bn1 * (KNB * DIM));
            #pragma unroll
            for (int k = 0; k < 6; ++k) nA[k] = nsrc[node * (KNB * 32) + k * 32 + c4];
            evN = *(const float4*)(ext_g + (bn1 + node) * DIM + c4 * 4);
            if (tid < M1) nwN = nw_g[bn1 * KNB + tid];
        }
        {
            bf16x8 Bf[8];                                // 2 n-tiles x 4 ks
            #pragma unroll
            for (int ks = 0; ks < 4; ++ks) {
                Bf[ks]     = w1fv[(nt0 * 4 + ks) * 64 + lane];
                Bf[4 + ks] = w1fv[(nt1 * 4 + ks) * 64 + lane];
            }
            #pragma unroll
            for (int mt = 0; mt < 6; ++mt) {
                const int rowbase = mt * 16 + quad * 4;
                bf16x8 af[4];
                #pragma unroll
                for (int ks = 0; ks < 4; ++ks)
                    af[ks] = *(const bf16x8*)&featb[(mt * 16 + m) * LDA1 + ks * 32 + quad * 8];

                f32x4 acc0 = {0.f, 0.f, 0.f, 0.f}, acc1 = {0.f, 0.f, 0.f, 0.f};
                #pragma unroll
                for (int ks = 0; ks < 4; ++ks) {
                    acc0 = __builtin_amdgcn_mfma_f32_16x16x32_bf16(af[ks], Bf[ks],     acc0, 0, 0, 0);
                    acc1 = __builtin_amdgcn_mfma_f32_16x16x32_bf16(af[ks], Bf[4 + ks], acc1, 0, 0, 0);
                }
                float lp[4];
                #pragma unroll
                for (int r = 0; r < 4; ++r) {
                    const float nwr = nwv[rowbase + r];
                    float v0 = acc0[r] + nwr * w1l0;
                    float v1 = acc1[r] + nwr * w1l1;
                    v0 = v0 > 0.f ? v0 : 0.2f * v0;
                    v1 = v1 > 0.f ? v1 : 0.2f * v1;
                    lp[r] = v0 * w2v0 + v1 * w2v1;
                }
                #pragma unroll
                for (int r = 0; r < 4; ++r) {
                    float v = lp[r];
                    v += __shfl_xor(v, 1, 64); v += __shfl_xor(v, 2, 64);
                    v += __shfl_xor(v, 4, 64); v += __shfl_xor(v, 8, 64);
                    if (m == 0) logits_p[wv][rowbase + r] = v;
                }
            }
        }
        bar_lds();

        // ---- phase 1: A2 self-stage(g) || softmax(g); reload self for g+1 ----
        {
            uint2 p; p.x = pack2(selfC.x, selfC.y); p.y = pack2(selfC.z, selfC.w);
            *(uint2*)&A2[node * LDA2 + c4 * 4] = p;
        }
        if (tid < T1) {
            float l[KNB];
            #pragma unroll
            for (int k = 0; k < KNB; ++k)
                l[k] = logits_p[0][tid * KNB + k] + logits_p[1][tid * KNB + k]
                     + logits_p[2][tid * KNB + k] + logits_p[3][tid * KNB + k];
            float mx = l[0];
            #pragma unroll
            for (int k = 1; k < KNB; ++k) mx = fmaxf(mx, l[k]);
            float s = 0.f;
            #pragma unroll
            for (int k = 0; k < KNB; ++k) { l[k] = __expf(l[k] - mx); s += l[k]; }
            const float inv = 1.f / s;
            #pragma unroll
            for (int k = 0; k < KNB; ++k) wts[tid * KNB + k] = l[k] * inv;
        }
        if (hasNext)
            selfC = *(const float4*)(selfv + (bn1 + node) * DIM + c4 * 4);
        bar_lds();

        // ---- phase 2: issue second-half prefetch for g+1, then agg(g) ----
        if (hasNext) {
            const float4* nsrc = (const float4*)(nbr_g + bn1 * (KNB * DIM));
            #pragma unroll
            for (int k = 0; k < 6; ++k) nB[k] = nsrc[node * (KNB * 32) + (k + 6) * 32 + c4];
        }
        {
            const int dd = c4 * 4;
            float s0 = 0.f, s1 = 0.f, s2 = 0.f, s3 = 0.f;
            #pragma unroll
            for (int k = 0; k < KNB; ++k) {
                const float w = wts[node * KNB + k];
                uint2 pf = *(const uint2*)&featb[(node * KNB + k) * LDA1 + dd];
                float2 lo = unpack2(pf.x), hi = unpack2(pf.y);
                s0 += w * lo.x; s1 += w * lo.y; s2 += w * hi.x; s3 += w * hi.y;
            }
            const float a0 = fabsf(evC.x) > 1e-30f ? s0 / evC.x : 0.f;
            const float a1 = fabsf(evC.y) > 1e-30f ? s1 / evC.y : 0.f;
            const float a2 = fabsf(evC.z) > 1e-30f ? s2 / evC.z : 0.f;
            const float a3 = fabsf(evC.w) > 1e-30f ? s3 / evC.w : 0.f;
            uint2 po; po.x = pack2(a0, a1); po.y = pack2(a2, a3);
            *(uint2*)&A2[node * LDA2 + 128 + dd] = po;
        }
        bar_lds();

        // ---- phase 3: featb(g+1) first half; GEMM2(g); featb(g+1) 2nd half ----
        if (hasNext) {
            #pragma unroll
            for (int k = 0; k < 6; ++k) {
                uint2 pf;
                pf.x = pack2(nA[k].x * evN.x, nA[k].y * evN.y);
                pf.y = pack2(nA[k].z * evN.z, nA[k].w * evN.w);
                *(uint2*)&featb[(node * KNB + k) * LDA1 + c4 * 4] = pf;
            }
            if (tid < M1) nwv[tid] = nwN;
        }
        {
            bf16x8 af2[8];
            #pragma unroll
            for (int ks = 0; ks < 8; ++ks)
                af2[ks] = *(const bf16x8*)&A2[m * LDA2 + ks * 32 + quad * 8];

            #pragma unroll
            for (int t = 0; t < 2; ++t) {
                const int nt = wv * 2 + t;
                f32x4 acc = {0.f, 0.f, 0.f, 0.f};
                #pragma unroll
                for (int ks = 0; ks < 8; ++ks)
                    acc = __builtin_amdgcn_mfma_f32_16x16x32_bf16(af2[ks], w3fv[(nt * 8 + ks) * 64 + lane], acc, 0, 0, 0);
                #pragma unroll
                for (int r = 0; r < 4; ++r) {
                    const int rl = quad * 4 + r;
                    if (rl < T1)
                        out[(bn0 + rl) * DIM + nt * 16 + m] = fmaxf(acc[r], 0.f);
                }
            }
        }
        if (hasNext) {
            #pragma unroll
            for (int k = 0; k < 6; ++k) {
                uint2 pf;
                pf.x = pack2(nB[k].x * evN.x, nB[k].y * evN.y);
                pf.y = pack2(nB[k].z * evN.z, nB[k].w * evN.w);
                *(uint2*)&featb[(node * KNB + (k + 6)) * LDA1 + c4 * 4] = pf;
            }
            evC = evN;
        }
        bar_lds();
    }
}

// ===========================================================================
// Fallback fp32 path if ws can't hold the 96 KB weight fragments.
// ===========================================================================
__global__ __launch_bounds__(128) void attn_agg_fb(
    const float* __restrict__ neighbor, const float* __restrict__ nw,
    const float* __restrict__ extra, const float* __restrict__ w1,
    const float* __restrict__ w2, float* __restrict__ agg)
{
    __shared__ float nbr_lds[2][KNB * DIM];
    const int wave = threadIdx.x >> 6, lane = threadIdx.x & 63;
    const int bn = blockIdx.x * 2 + wave;
    const float* nbr_gp = neighbor + (size_t)bn * (KNB * DIM);
    const float* ext_gp = extra + (size_t)bn * DIM;
    {
        const float4* s = (const float4*)nbr_gp;
        float4* d4 = (float4*)nbr_lds[wave];
        #pragma unroll
        for (int j = 0; j < 6; ++j) d4[lane + j * 64] = s[lane + j * 64];
    }
    __syncthreads();
    const int d0 = lane, d1 = lane + 64;
    float acc0[KNB], acc1[KNB];
    #pragma unroll
    for (int k = 0; k < KNB; ++k) { acc0[k] = 0.f; acc1[k] = 0.f; }
    const float* nbr_s = nbr_lds[wave];
    for (int f = 0; f < DIM; f += 4) {
        float4 ev = *(const float4*)(ext_gp + f);
        float q0[4], q1[4];
        #pragma unroll
        for (int j = 0; j < 4; ++j) {
            q0[j] = ((const float*)&ev)[j] * w1[(f + j) * DIM + d0];
            q1[j] = ((const float*)&ev)[j] * w1[(f + j) * DIM + d1];
        }
        #pragma unroll
        for (int k = 0; k < KNB; ++k) {
            float4 nv = *(const float4*)(nbr_s + k * DIM + f);
            acc0[k] += nv.x * q0[0] + nv.y * q0[1] + nv.z * q0[2] + nv.w * q0[3];
            acc1[k] += nv.x * q1[0] + nv.y * q1[1] + nv.z * q1[2] + nv.w * q1[3];
        }
    }
    const float* nwp = nw + (size_t)bn * KNB;
    const float w1t0 = w1[DIM * DIM + d0], w1t1 = w1[DIM * DIM + d1];
    const float w2a = w2[d0], w2b = w2[d1];
    float part[KNB];
    #pragma unroll
    for (int k = 0; k < KNB; ++k) {
        float a0 = acc0[k] + nwp[k] * w1t0, a1 = acc1[k] + nwp[k] * w1t1;
        a0 = a0 > 0.f ? a0 : 0.2f * a0; a1 = a1 > 0.f ? a1 : 0.2f * a1;
        part[k] = a0 * w2a + a1 * w2b;
    }
    #pragma unroll
    for (int k = 0; k < KNB; ++k) {
        float v = part[k];
        #pragma unroll
        for (int off = 32; off > 0; off >>= 1) v += __shfl_xor(v, off, 64);
        part[k] = v;
    }
    float mx = part[0];
    #pragma unroll
    for (int k = 1; k < KNB; ++k) mx = fmaxf(mx, part[k]);
    float s = 0.f;
    #pragma unroll
    for (int k = 0; k < KNB; ++k) { part[k] = __expf(part[k] - mx); s += part[k]; }
    const float inv = 1.f / s;
    float a0 = 0.f, a1 = 0.f;
    #pragma unroll
    for (int k = 0; k < KNB; ++k) {
        const float aw = part[k] * inv;
        a0 += aw * nbr_s[k * DIM + d0]; a1 += aw * nbr_s[k * DIM + d1];
    }
    agg[(size_t)bn * DIM + d0] = a0; agg[(size_t)bn * DIM + d1] = a1;
}

__global__ __launch_bounds__(256) void out_gemm_fb(
    const float* __restrict__ selfv, const float* __restrict__ agg,
    const float* __restrict__ w3, float* __restrict__ out)
{
    __shared__ float in_lds[64][256];
    const int row0 = blockIdx.x * 64, tid = threadIdx.x;
    for (int idx = tid; idx < 64 * 64; idx += 256) {
        const int r = idx >> 6, c4 = idx & 63;
        float4 v;
        if (c4 < 32) v = ((const float4*)(selfv + (size_t)(row0 + r) * DIM))[c4];
        else         v = ((const float4*)(agg + (size_t)(row0 + r) * DIM))[c4 - 32];
        ((float4*)in_lds[r])[c4] = v;
    }
    __syncthreads();
    const int d0 = tid & 63, rbase = (tid >> 6) * 16;
    float acc0[16], acc1[16];
    #pragma unroll
    for (int r = 0; r < 16; ++r) { acc0[r] = 0.f; acc1[r] = 0.f; }
    for (int f = 0; f < 256; f += 4) {
        float w3a[4], w3b[4];
        #pragma unroll
        for (int j = 0; j < 4; ++j) {
            w3a[j] = w3[(f + j) * DIM + d0]; w3b[j] = w3[(f + j) * DIM + d0 + 64];
        }
        #pragma unroll
        for (int r = 0; r < 16; ++r) {
            float4 iv = *(const float4*)(&in_lds[rbase + r][f]);
            acc0[r] += iv.x * w3a[0] + iv.y * w3a[1] + iv.z * w3a[2] + iv.w * w3a[3];
            acc1[r] += iv.x * w3b[0] + iv.y * w3b[1] + iv.z * w3b[2] + iv.w * w3b[3];
        }
    }
    #pragma unroll
    for (int r = 0; r < 16; ++r) {
        const size_t row = (size_t)(row0 + rbase + r);
        out[row * DIM + d0] = fmaxf(acc0[r], 0.f);
        out[row * DIM + d0 + 64] = fmaxf(acc1[r], 0.f);
    }
}

// ---------------------------------------------------------------------------
extern "C" void kernel_launch(void* const* d_in, const int* in_sizes, int n_in,
                              void* d_out, int out_size, void* d_ws, size_t ws_size,
                              hipStream_t stream) {
    const float* selfv    = (const float*)d_in[0];
    const float* neighbor = (const float*)d_in[1];
    const float* nw       = (const float*)d_in[4];
    const float* extra    = (const float*)d_in[5];
    const float* w1       = (const float*)d_in[6];
    const float* w2       = (const float*)d_in[7];
    const float* w3       = (const float*)d_in[8];
    float* out = (float*)d_out;

    // ws layout: [0,32K) w1f bf16 | [32K,96K) w3f bf16
    if (ws_size >= (size_t)96 * 1024) {
        unsigned short* w1f = (unsigned short*)d_ws;
        unsigned short* w3f = (unsigned short*)((char*)d_ws + 32 * 1024);
        prep_kernel<<<128, 256, 0, stream>>>(w1, w3, w1f, w3f);
        fused_kernel<<<BN / (T1 * NG), 256, 0, stream>>>(neighbor, nw, extra, selfv,
                                                         w1, w2, w1f, w3f, out);
    } else {
        attn_agg_fb<<<BN / 2, 128, 0, stream>>>(neighbor, nw, extra, w1, w2, out);
        out_gemm_fb<<<BN / 64, 256, 0, stream>>>(selfv, out, w3, out);
    }
}

// Round 2
// 340.084 us; speedup vs baseline: 1.2284x; 1.2284x over previous
//
#include <hip/hip_runtime.h>
#include <hip/hip_bf16.h>

#define BN    32768   // B*N
#define KNB   12
#define DIM   128

typedef __attribute__((ext_vector_type(8))) short bf16x8;
typedef __attribute__((ext_vector_type(4))) float f32x4;

__device__ inline unsigned short f2b(float x) {
    union { float f; unsigned u; } v; v.f = x;
    unsigned r = v.u + 0x7fffu + ((v.u >> 16) & 1u);   // RNE
    return (unsigned short)(r >> 16);
}
__device__ inline unsigned pack2(float a, float b) {   // v_cvt_pk_bf16_f32 on gfx950
    __hip_bfloat162 h = __float22bfloat162_rn(make_float2(a, b));
    unsigned u; __builtin_memcpy(&u, &h, 4); return u;
}
__device__ inline float2 unpack2(unsigned u) {
    __hip_bfloat162 h; __builtin_memcpy(&h, &u, 4);
    return __bfloat1622float2(h);
}

// Raw barrier: publish LDS (lgkmcnt) but do NOT drain vmcnt — keeps the
// cross-group global-load prefetch in flight across phase boundaries.
// (__syncthreads would emit s_waitcnt vmcnt(0) and kill the pipeline.)
__device__ inline void bar_lds() {
    asm volatile("s_waitcnt lgkmcnt(0)" ::: "memory");
    __builtin_amdgcn_s_barrier();
    asm volatile("" ::: "memory");
}

// ---------------------------------------------------------------------------
// Prep: w1 (128x128 part) and w3 (256x128) -> bf16 MFMA B-fragment order.
// frag fi, lane, j -> B[k = ks*32 + (lane>>4)*8 + j][n = nt*16 + (lane&15)]
// w1f: fi = nt*4 + ks;  w3f: fi = nt*8 + ks
// ---------------------------------------------------------------------------
__global__ void prep_kernel(const float* __restrict__ w1, const float* __restrict__ w3,
                            unsigned short* __restrict__ w1f, unsigned short* __restrict__ w3f) {
    int idx = blockIdx.x * 256 + threadIdx.x;
    if (idx < 16384) {
        int j = idx & 7, lane = (idx >> 3) & 63, fi = idx >> 9;
        int nt = fi >> 2, ks = fi & 3;
        int k = ks * 32 + (lane >> 4) * 8 + j;
        int n = nt * 16 + (lane & 15);
        w1f[idx] = f2b(w1[k * DIM + n]);
    }
    if (idx < 32768) {
        int j = idx & 7, lane = (idx >> 3) & 63, fi = idx >> 9;
        int nt = fi >> 3, ks = fi & 7;
        int k = ks * 32 + (lane >> 4) * 8 + j;
        int n = nt * 16 + (lane & 15);
        w3f[idx] = f2b(w3[k * DIM + n]);
    }
}

// ---------------------------------------------------------------------------
// Fused kernel, block = 8 nodes/group (M1 = 96 (node,k) rows), NG=4 groups
// per block with a cross-group prefetch pipeline (spill-free edition):
//   phase 0: issue nbr k=0..5 / ext / nw loads for g+1, self load for g;
//            GEMM1(g)
//   phase 1: A2 self-stage(g) || softmax(g)
//   phase 2: convert nA->pfA (bf16, halves reg state); issue nbr k=6..11
//            loads for g+1; agg(g)
//   phase 3: write pfA -> featb; GEMM2(g); convert+write nB -> featb
// Pipeline state across phases: pfA 12 + nB 24 + evC/evN 8 + nwN 1 ~ 45 VGPR.
// No launch-bounds occupancy floor: round-1's (256,4) forced a 64-VGPR
// target -> 293 MB of scratch spill writes (WRITE_SIZE 310 MB vs 17 ideal).
// ---------------------------------------------------------------------------
#define T1   8
#define NG   4
#define M1   96
#define LDA1 136    // shorts; 16B-multiple (b128-aligned), +8 pad
#define LDA2 264    // shorts; 16B-multiple, +8 pad

__global__ __launch_bounds__(256) void fused_kernel(
    const float* __restrict__ nbr_g,   // [BN,12,128]
    const float* __restrict__ nw_g,    // [BN,12]
    const float* __restrict__ ext_g,   // [BN,128]
    const float* __restrict__ selfv,   // [BN,128]
    const float* __restrict__ w1,      // [129,128] (row 128 used in epilogue)
    const float* __restrict__ w2,      // [128]
    const unsigned short* __restrict__ w1f,
    const unsigned short* __restrict__ w3f,
    float* __restrict__ out)           // [BN,128]
{
    __shared__ unsigned short featb[M1 * LDA1];          // 26112 B
    __shared__ unsigned short A2[16 * LDA2];             // 8448 B
    __shared__ float logits_p[4][M1];                    // 1536 B
    __shared__ float wts[M1];                            // 384 B
    __shared__ float nwv[M1];                            // 384 B

    const int tid  = threadIdx.x;
    const int lane = tid & 63;
    const int wv   = tid >> 6;

    const int node = tid >> 5;          // 0..7
    const int c4   = tid & 31;          // float4 column

    const int m    = lane & 15;
    const int quad = lane >> 4;
    const int nt0  = wv * 2;
    const int nt1  = wv * 2 + 1;

    // group-invariant weight scalars (per-lane)
    const float w2v0 = w2[nt0 * 16 + m], w2v1 = w2[nt1 * 16 + m];
    const float w1l0 = w1[DIM * DIM + nt0 * 16 + m];
    const float w1l1 = w1[DIM * DIM + nt1 * 16 + m];
    const bf16x8* w1fv = (const bf16x8*)w1f;
    const bf16x8* w3fv = (const bf16x8*)w3f;

    const size_t base = (size_t)blockIdx.x * (NG * T1);   // first node row

    // pipeline registers
    float4 nA[6];          // f32 prefetch, first half (dies in phase 2)
    uint2  pfA[6];         // packed bf16 feat, first half (phase 2 -> 3)
    float4 nB[6];          // f32 prefetch, second half (phase 2 -> 3)
    float4 evC, evN;

    // ---- prologue: stage group 0 fully ----
    {
        const float4* nsrc = (const float4*)(nbr_g + base * (KNB * DIM));
        evC = *(const float4*)(ext_g + (base + node) * DIM + c4 * 4);
        float nw0 = 0.f;
        if (tid < M1) nw0 = nw_g[base * KNB + tid];
        float4 nv[KNB];
        #pragma unroll
        for (int k = 0; k < KNB; ++k) nv[k] = nsrc[node * (KNB * 32) + k * 32 + c4];
        #pragma unroll
        for (int k = 0; k < KNB; ++k) {
            uint2 pf;
            pf.x = pack2(nv[k].x * evC.x, nv[k].y * evC.y);
            pf.y = pack2(nv[k].z * evC.z, nv[k].w * evC.w);
            *(uint2*)&featb[(node * KNB + k) * LDA1 + c4 * 4] = pf;
        }
        if (tid < M1) nwv[tid] = nw0;
    }
    bar_lds();

    #pragma unroll 1
    for (int g = 0; g < NG; ++g) {
        const size_t bn0 = base + (size_t)g * T1;
        const size_t bn1 = bn0 + T1;
        const bool hasNext = (g + 1 < NG);
        float nwN = 0.f;
        float4 selfg;

        // ---- phase 0: issue prefetches, then GEMM1(g) ----
        if (hasNext) {
            const float4* nsrc = (const float4*)(nbr_g + bn1 * (KNB * DIM));
            #pragma unroll
            for (int k = 0; k < 6; ++k) nA[k] = nsrc[node * (KNB * 32) + k * 32 + c4];
            evN = *(const float4*)(ext_g + (bn1 + node) * DIM + c4 * 4);
            if (tid < M1) nwN = nw_g[bn1 * KNB + tid];
        }
        selfg = *(const float4*)(selfv + (bn0 + node) * DIM + c4 * 4);
        {
            bf16x8 Bf[8];                                // 2 n-tiles x 4 ks
            #pragma unroll
            for (int ks = 0; ks < 4; ++ks) {
                Bf[ks]     = w1fv[(nt0 * 4 + ks) * 64 + lane];
                Bf[4 + ks] = w1fv[(nt1 * 4 + ks) * 64 + lane];
            }
            #pragma unroll
            for (int mt = 0; mt < 6; ++mt) {
                const int rowbase = mt * 16 + quad * 4;
                bf16x8 af[4];
                #pragma unroll
                for (int ks = 0; ks < 4; ++ks)
                    af[ks] = *(const bf16x8*)&featb[(mt * 16 + m) * LDA1 + ks * 32 + quad * 8];

                f32x4 acc0 = {0.f, 0.f, 0.f, 0.f}, acc1 = {0.f, 0.f, 0.f, 0.f};
                #pragma unroll
                for (int ks = 0; ks < 4; ++ks) {
                    acc0 = __builtin_amdgcn_mfma_f32_16x16x32_bf16(af[ks], Bf[ks],     acc0, 0, 0, 0);
                    acc1 = __builtin_amdgcn_mfma_f32_16x16x32_bf16(af[ks], Bf[4 + ks], acc1, 0, 0, 0);
                }
                float lp[4];
                #pragma unroll
                for (int r = 0; r < 4; ++r) {
                    const float nwr = nwv[rowbase + r];
                    float v0 = acc0[r] + nwr * w1l0;
                    float v1 = acc1[r] + nwr * w1l1;
                    v0 = v0 > 0.f ? v0 : 0.2f * v0;
                    v1 = v1 > 0.f ? v1 : 0.2f * v1;
                    lp[r] = v0 * w2v0 + v1 * w2v1;
                }
                #pragma unroll
                for (int r = 0; r < 4; ++r) {
                    float v = lp[r];
                    v += __shfl_xor(v, 1, 64); v += __shfl_xor(v, 2, 64);
                    v += __shfl_xor(v, 4, 64); v += __shfl_xor(v, 8, 64);
                    if (m == 0) logits_p[wv][rowbase + r] = v;
                }
            }
        }
        bar_lds();

        // ---- phase 1: A2 self-stage(g) || softmax(g) ----
        {
            uint2 p; p.x = pack2(selfg.x, selfg.y); p.y = pack2(selfg.z, selfg.w);
            *(uint2*)&A2[node * LDA2 + c4 * 4] = p;
        }
        if (tid < T1) {
            float l[KNB];
            #pragma unroll
            for (int k = 0; k < KNB; ++k)
                l[k] = logits_p[0][tid * KNB + k] + logits_p[1][tid * KNB + k]
                     + logits_p[2][tid * KNB + k] + logits_p[3][tid * KNB + k];
            float mx = l[0];
            #pragma unroll
            for (int k = 1; k < KNB; ++k) mx = fmaxf(mx, l[k]);
            float s = 0.f;
            #pragma unroll
            for (int k = 0; k < KNB; ++k) { l[k] = __expf(l[k] - mx); s += l[k]; }
            const float inv = 1.f / s;
            #pragma unroll
            for (int k = 0; k < KNB; ++k) wts[tid * KNB + k] = l[k] * inv;
        }
        bar_lds();

        // ---- phase 2: convert nA -> pfA; issue nB loads; agg(g) ----
        if (hasNext) {
            #pragma unroll
            for (int k = 0; k < 6; ++k) {
                pfA[k].x = pack2(nA[k].x * evN.x, nA[k].y * evN.y);
                pfA[k].y = pack2(nA[k].z * evN.z, nA[k].w * evN.w);
            }
            const float4* nsrc = (const float4*)(nbr_g + bn1 * (KNB * DIM));
            #pragma unroll
            for (int k = 0; k < 6; ++k) nB[k] = nsrc[node * (KNB * 32) + (k + 6) * 32 + c4];
        }
        {
            const int dd = c4 * 4;
            float s0 = 0.f, s1 = 0.f, s2 = 0.f, s3 = 0.f;
            #pragma unroll
            for (int k = 0; k < KNB; ++k) {
                const float w = wts[node * KNB + k];
                uint2 pf = *(const uint2*)&featb[(node * KNB + k) * LDA1 + dd];
                float2 lo = unpack2(pf.x), hi = unpack2(pf.y);
                s0 += w * lo.x; s1 += w * lo.y; s2 += w * hi.x; s3 += w * hi.y;
            }
            const float a0 = fabsf(evC.x) > 1e-30f ? s0 / evC.x : 0.f;
            const float a1 = fabsf(evC.y) > 1e-30f ? s1 / evC.y : 0.f;
            const float a2 = fabsf(evC.z) > 1e-30f ? s2 / evC.z : 0.f;
            const float a3 = fabsf(evC.w) > 1e-30f ? s3 / evC.w : 0.f;
            uint2 po; po.x = pack2(a0, a1); po.y = pack2(a2, a3);
            *(uint2*)&A2[node * LDA2 + 128 + dd] = po;
        }
        bar_lds();

        // ---- phase 3: write pfA -> featb; GEMM2(g); convert+write nB ----
        if (hasNext) {
            #pragma unroll
            for (int k = 0; k < 6; ++k)
                *(uint2*)&featb[(node * KNB + k) * LDA1 + c4 * 4] = pfA[k];
            if (tid < M1) nwv[tid] = nwN;
        }
        {
            bf16x8 af2[8];
            #pragma unroll
            for (int ks = 0; ks < 8; ++ks)
                af2[ks] = *(const bf16x8*)&A2[m * LDA2 + ks * 32 + quad * 8];

            #pragma unroll
            for (int t = 0; t < 2; ++t) {
                const int nt = wv * 2 + t;
                f32x4 acc = {0.f, 0.f, 0.f, 0.f};
                #pragma unroll
                for (int ks = 0; ks < 8; ++ks)
                    acc = __builtin_amdgcn_mfma_f32_16x16x32_bf16(af2[ks], w3fv[(nt * 8 + ks) * 64 + lane], acc, 0, 0, 0);
                #pragma unroll
                for (int r = 0; r < 4; ++r) {
                    const int rl = quad * 4 + r;
                    if (rl < T1)
                        out[(bn0 + rl) * DIM + nt * 16 + m] = fmaxf(acc[r], 0.f);
                }
            }
        }
        if (hasNext) {
            #pragma unroll
            for (int k = 0; k < 6; ++k) {
                uint2 pf;
                pf.x = pack2(nB[k].x * evN.x, nB[k].y * evN.y);
                pf.y = pack2(nB[k].z * evN.z, nB[k].w * evN.w);
                *(uint2*)&featb[(node * KNB + (k + 6)) * LDA1 + c4 * 4] = pf;
            }
            evC = evN;
        }
        bar_lds();
    }
}

// ===========================================================================
// Fallback fp32 path if ws can't hold the 96 KB weight fragments.
// ===========================================================================
__global__ __launch_bounds__(128) void attn_agg_fb(
    const float* __restrict__ neighbor, const float* __restrict__ nw,
    const float* __restrict__ extra, const float* __restrict__ w1,
    const float* __restrict__ w2, float* __restrict__ agg)
{
    __shared__ float nbr_lds[2][KNB * DIM];
    const int wave = threadIdx.x >> 6, lane = threadIdx.x & 63;
    const int bn = blockIdx.x * 2 + wave;
    const float* nbr_gp = neighbor + (size_t)bn * (KNB * DIM);
    const float* ext_gp = extra + (size_t)bn * DIM;
    {
        const float4* s = (const float4*)nbr_gp;
        float4* d4 = (float4*)nbr_lds[wave];
        #pragma unroll
        for (int j = 0; j < 6; ++j) d4[lane + j * 64] = s[lane + j * 64];
    }
    __syncthreads();
    const int d0 = lane, d1 = lane + 64;
    float acc0[KNB], acc1[KNB];
    #pragma unroll
    for (int k = 0; k < KNB; ++k) { acc0[k] = 0.f; acc1[k] = 0.f; }
    const float* nbr_s = nbr_lds[wave];
    for (int f = 0; f < DIM; f += 4) {
        float4 ev = *(const float4*)(ext_gp + f);
        float q0[4], q1[4];
        #pragma unroll
        for (int j = 0; j < 4; ++j) {
            q0[j] = ((const float*)&ev)[j] * w1[(f + j) * DIM + d0];
            q1[j] = ((const float*)&ev)[j] * w1[(f + j) * DIM + d1];
        }
        #pragma unroll
        for (int k = 0; k < KNB; ++k) {
            float4 nv = *(const float4*)(nbr_s + k * DIM + f);
            acc0[k] += nv.x * q0[0] + nv.y * q0[1] + nv.z * q0[2] + nv.w * q0[3];
            acc1[k] += nv.x * q1[0] + nv.y * q1[1] + nv.z * q1[2] + nv.w * q1[3];
        }
    }
    const float* nwp = nw + (size_t)bn * KNB;
    const float w1t0 = w1[DIM * DIM + d0], w1t1 = w1[DIM * DIM + d1];
    const float w2a = w2[d0], w2b = w2[d1];
    float part[KNB];
    #pragma unroll
    for (int k = 0; k < KNB; ++k) {
        float a0 = acc0[k] + nwp[k] * w1t0, a1 = acc1[k] + nwp[k] * w1t1;
        a0 = a0 > 0.f ? a0 : 0.2f * a0; a1 = a1 > 0.f ? a1 : 0.2f * a1;
        part[k] = a0 * w2a + a1 * w2b;
    }
    #pragma unroll
    for (int k = 0; k < KNB; ++k) {
        float v = part[k];
        #pragma unroll
        for (int off = 32; off > 0; off >>= 1) v += __shfl_xor(v, off, 64);
        part[k] = v;
    }
    float mx = part[0];
    #pragma unroll
    for (int k = 1; k < KNB; ++k) mx = fmaxf(mx, part[k]);
    float s = 0.f;
    #pragma unroll
    for (int k = 0; k < KNB; ++k) { part[k] = __expf(part[k] - mx); s += part[k]; }
    const float inv = 1.f / s;
    float a0 = 0.f, a1 = 0.f;
    #pragma unroll
    for (int k = 0; k < KNB; ++k) {
        const float aw = part[k] * inv;
        a0 += aw * nbr_s[k * DIM + d0]; a1 += aw * nbr_s[k * DIM + d1];
    }
    agg[(size_t)bn * DIM + d0] = a0; agg[(size_t)bn * DIM + d1] = a1;
}

__global__ __launch_bounds__(256) void out_gemm_fb(
    const float* __restrict__ selfv, const float* __restrict__ agg,
    const float* __restrict__ w3, float* __restrict__ out)
{
    __shared__ float in_lds[64][256];
    const int row0 = blockIdx.x * 64, tid = threadIdx.x;
    for (int idx = tid; idx < 64 * 64; idx += 256) {
        const int r = idx >> 6, c4 = idx & 63;
        float4 v;
        if (c4 < 32) v = ((const float4*)(selfv + (size_t)(row0 + r) * DIM))[c4];
        else         v = ((const float4*)(agg + (size_t)(row0 + r) * DIM))[c4 - 32];
        ((float4*)in_lds[r])[c4] = v;
    }
    __syncthreads();
    const int d0 = tid & 63, rbase = (tid >> 6) * 16;
    float acc0[16], acc1[16];
    #pragma unroll
    for (int r = 0; r < 16; ++r) { acc0[r] = 0.f; acc1[r] = 0.f; }
    for (int f = 0; f < 256; f += 4) {
        float w3a[4], w3b[4];
        #pragma unroll
        for (int j = 0; j < 4; ++j) {
            w3a[j] = w3[(f + j) * DIM + d0]; w3b[j] = w3[(f + j) * DIM + d0 + 64];
        }
        #pragma unroll
        for (int r = 0; r < 16; ++r) {
            float4 iv = *(const float4*)(&in_lds[rbase + r][f]);
            acc0[r] += iv.x * w3a[0] + iv.y * w3a[1] + iv.z * w3a[2] + iv.w * w3a[3];
            acc1[r] += iv.x * w3b[0] + iv.y * w3b[1] + iv.z * w3b[2] + iv.w * w3b[3];
        }
    }
    #pragma unroll
    for (int r = 0; r < 16; ++r) {
        const size_t row = (size_t)(row0 + rbase + r);
        out[row * DIM + d0] = fmaxf(acc0[r], 0.f);
        out[row * DIM + d0 + 64] = fmaxf(acc1[r], 0.f);
    }
}

// ---------------------------------------------------------------------------
extern "C" void kernel_launch(void* const* d_in, const int* in_sizes, int n_in,
                              void* d_out, int out_size, void* d_ws, size_t ws_size,
                              hipStream_t stream) {
    const float* selfv    = (const float*)d_in[0];
    const float* neighbor = (const float*)d_in[1];
    const float* nw       = (const float*)d_in[4];
    const float* extra    = (const float*)d_in[5];
    const float* w1       = (const float*)d_in[6];
    const float* w2       = (const float*)d_in[7];
    const float* w3       = (const float*)d_in[8];
    float* out = (float*)d_out;

    // ws layout: [0,32K) w1f bf16 | [32K,96K) w3f bf16
    if (ws_size >= (size_t)96 * 1024) {
        unsigned short* w1f = (unsigned short*)d_ws;
        unsigned short* w3f = (unsigned short*)((char*)d_ws + 32 * 1024);
        prep_kernel<<<128, 256, 0, stream>>>(w1, w3, w1f, w3f);
        fused_kernel<<<BN / (T1 * NG), 256, 0, stream>>>(neighbor, nw, extra, selfv,
                                                         w1, w2, w1f, w3f, out);
    } else {
        attn_agg_fb<<<BN / 2, 128, 0, stream>>>(neighbor, nw, extra, w1, w2, out);
        out_gemm_fb<<<BN / 64, 256, 0, stream>>>(selfv, out, w3, out);
    }
}